// Round 1
// baseline (12712.017 us; speedup 1.0000x reference)
//
#include <hip/hip_runtime.h>
#include <hip/hip_bf16.h>

// Problem constants (from reference): N=500000, D=64, K=512.
// out rows: [0,K)=xw_sum, [K,2K)=w_sum, row 2K = inertia broadcast to 64 cols.

#define D_DIM 64
#define K_CLUS 512

// ---------------- Kernel 1: centroid squared norms ----------------
__global__ void cc_kernel(const float* __restrict__ C, float* __restrict__ CC, int k_total) {
    int k = blockIdx.x * blockDim.x + threadIdx.x;
    if (k >= k_total) return;
    const float4* cp = (const float4*)(C + (size_t)k * D_DIM);
    float s = 0.f;
#pragma unroll
    for (int i = 0; i < 16; ++i) {
        float4 c = cp[i];
        s += c.x * c.x + c.y * c.y + c.z * c.z + c.w * c.w;
    }
    CC[k] = s;
}

// ---------------- Kernel 2: assignment + inertia ----------------
__global__ __launch_bounds__(256) void assign_kernel(
        const float* __restrict__ X, const float* __restrict__ C,
        const float* __restrict__ CC, int* __restrict__ y,
        float* __restrict__ out, int n) {
    int row = blockIdx.x * blockDim.x + threadIdx.x;
    float mind = 0.f;
    if (row < n) {
        float4 x[16];
        const float4* xp = (const float4*)(X + (size_t)row * D_DIM);
#pragma unroll
        for (int i = 0; i < 16; ++i) x[i] = xp[i];
        float xx = 0.f;
#pragma unroll
        for (int i = 0; i < 16; ++i)
            xx += x[i].x * x[i].x + x[i].y * x[i].y + x[i].z * x[i].z + x[i].w * x[i].w;

        float best = 3.4e38f;
        int bestk = 0;
        for (int k = 0; k < K_CLUS; ++k) {
            // k is wave-uniform -> centroid loads should scalarize (s_load),
            // freeing VMEM; v_fma with SGPR src.
            const float4* cp = (const float4*)(C + (size_t)k * D_DIM);
            float dot = 0.f;
#pragma unroll
            for (int i = 0; i < 16; ++i) {
                float4 c = cp[i];
                dot += x[i].x * c.x + x[i].y * c.y + x[i].z * c.z + x[i].w * c.w;
            }
            float d2 = xx - 2.f * dot + CC[k];
            if (d2 < best) { best = d2; bestk = k; }   // first-min wins, matches argmin
        }
        y[row] = bestk;
        mind = sqrtf(fmaxf(best, 0.f) * (1.0f / (float)D_DIM));
    }
    // full-wave butterfly sum of min-distances (inactive rows contribute 0)
    float s = mind;
#pragma unroll
    for (int off = 32; off > 0; off >>= 1) s += __shfl_xor(s, off);
    // every lane holds the wave sum; lane i accumulates into inertia column i
    int lane = threadIdx.x & 63;
    atomicAdd(out + (size_t)(2 * K_CLUS) * D_DIM + lane, s * (1.0f / 64.0f) * 64.0f == 0.f ? s : s);
}

// ---------------- Kernel 3: segment-sum accumulation ----------------
__global__ __launch_bounds__(256) void accum_kernel(
        const float* __restrict__ X, const float* __restrict__ W,
        const int* __restrict__ y, float* __restrict__ out, int n) {
    int row = blockIdx.x * blockDim.x + threadIdx.x;
    if (row >= n) return;
    int k = y[row];
    const float4* xp = (const float4*)(X + (size_t)row * D_DIM);
    const float4* wp = (const float4*)(W + (size_t)row * D_DIM);
    float* xw = out + (size_t)k * D_DIM;
    float* wsum = out + (size_t)(K_CLUS + k) * D_DIM;
#pragma unroll
    for (int i = 0; i < 16; ++i) {
        float4 x = xp[i];
        float4 w = wp[i];
        atomicAdd(xw + 4 * i + 0, x.x * w.x);
        atomicAdd(xw + 4 * i + 1, x.y * w.y);
        atomicAdd(xw + 4 * i + 2, x.z * w.z);
        atomicAdd(xw + 4 * i + 3, x.w * w.w);
        atomicAdd(wsum + 4 * i + 0, w.x);
        atomicAdd(wsum + 4 * i + 1, w.y);
        atomicAdd(wsum + 4 * i + 2, w.z);
        atomicAdd(wsum + 4 * i + 3, w.w);
    }
}

extern "C" void kernel_launch(void* const* d_in, const int* in_sizes, int n_in,
                              void* d_out, int out_size, void* d_ws, size_t ws_size,
                              hipStream_t stream) {
    const float* X = (const float*)d_in[0];
    const float* C = (const float*)d_in[1];
    const float* W = (const float*)d_in[2];
    float* out = (float*)d_out;
    int n = in_sizes[0] / D_DIM;       // 500000
    int k_total = in_sizes[1] / D_DIM; // 512

    float* cc = (float*)d_ws;                       // 512 floats
    int* y = (int*)((char*)d_ws + 4096);            // n ints

    // output is accumulated via atomics -> must zero every call (graph replay safe)
    hipMemsetAsync(d_out, 0, (size_t)out_size * sizeof(float), stream);

    cc_kernel<<<(k_total + 255) / 256, 256, 0, stream>>>(C, cc, k_total);
    assign_kernel<<<(n + 255) / 256, 256, 0, stream>>>(X, C, cc, y, out, n);
    accum_kernel<<<(n + 255) / 256, 256, 0, stream>>>(X, W, y, out, n);
}

// Round 2
// 2456.436 us; speedup vs baseline: 5.1750x; 5.1750x over previous
//
#include <hip/hip_runtime.h>
#include <hip/hip_bf16.h>

// N=500000, D=64, K=512 (fp32).
// out rows: [0,K)=xw_sum, [K,2K)=w_sum, row 2K = inertia broadcast to 64 cols.

#define D_DIM 64
#define K_CLUS 512

// ---------------- Kernel 1: centroid squared norms ----------------
__global__ void cc_kernel(const float* __restrict__ C, float* __restrict__ CC, int k_total) {
    int k = blockIdx.x * blockDim.x + threadIdx.x;
    if (k >= k_total) return;
    const float4* cp = (const float4*)(C + (size_t)k * D_DIM);
    float s = 0.f;
#pragma unroll
    for (int i = 0; i < 16; ++i) {
        float4 c = cp[i];
        s += c.x * c.x + c.y * c.y + c.z * c.z + c.w * c.w;
    }
    CC[k] = s;
}

// ---------------- Kernel 2: assignment + histogram + inertia ----------------
__global__ __launch_bounds__(256) void assign_kernel(
        const float* __restrict__ X, const float* __restrict__ C,
        const float* __restrict__ CC, int* __restrict__ y,
        int* __restrict__ rank, int* __restrict__ count,
        float* __restrict__ inertia_ws, int n) {
    int row = blockIdx.x * blockDim.x + threadIdx.x;
    float mind = 0.f;
    if (row < n) {
        float4 x[16];
        const float4* xp = (const float4*)(X + (size_t)row * D_DIM);
#pragma unroll
        for (int i = 0; i < 16; ++i) x[i] = xp[i];
        float xx = 0.f;
#pragma unroll
        for (int i = 0; i < 16; ++i)
            xx += x[i].x * x[i].x + x[i].y * x[i].y + x[i].z * x[i].z + x[i].w * x[i].w;

        float best = 3.4e38f;
        int bestk = 0;
        for (int k = 0; k < K_CLUS; ++k) {
            const float4* cp = (const float4*)(C + (size_t)k * D_DIM);
            float dot = 0.f;
#pragma unroll
            for (int i = 0; i < 16; ++i) {
                float4 c = cp[i];
                dot += x[i].x * c.x + x[i].y * c.y + x[i].z * c.z + x[i].w * c.w;
            }
            float d2 = xx - 2.f * dot + CC[k];
            if (d2 < best) { best = d2; bestk = k; }   // first-min wins == argmin
        }
        y[row] = bestk;
        rank[row] = atomicAdd(&count[bestk], 1);       // int atomic, 512-way spread
        mind = sqrtf(fmaxf(best, 0.f) * (1.0f / (float)D_DIM));
    }
    // wave butterfly, then block reduce, then ONE float atomic per block
    float s = mind;
#pragma unroll
    for (int off = 32; off > 0; off >>= 1) s += __shfl_xor(s, off);
    __shared__ float wsum[4];
    int w = threadIdx.x >> 6;
    if ((threadIdx.x & 63) == 0) wsum[w] = s;
    __syncthreads();
    if (threadIdx.x == 0)
        atomicAdd(inertia_ws, wsum[0] + wsum[1] + wsum[2] + wsum[3]);
}

// ---------------- Kernel 3: exclusive prefix sum over 512 counts ----------------
__global__ __launch_bounds__(K_CLUS) void prefix_kernel(
        const int* __restrict__ count, int* __restrict__ offset) {
    __shared__ int tmp[K_CLUS];
    int t = threadIdx.x;
    tmp[t] = count[t];
    __syncthreads();
    for (int s = 1; s < K_CLUS; s <<= 1) {
        int v = (t >= s) ? tmp[t - s] : 0;
        __syncthreads();
        tmp[t] += v;
        __syncthreads();
    }
    offset[t] = tmp[t] - count[t];   // exclusive scan
}

// ---------------- Kernel 4: scatter rows into cluster-sorted order ----------------
__global__ __launch_bounds__(256) void scatter_kernel(
        const int* __restrict__ y, const int* __restrict__ rank,
        const int* __restrict__ offset, int* __restrict__ sorted, int n) {
    int row = blockIdx.x * blockDim.x + threadIdx.x;
    if (row >= n) return;
    sorted[offset[y[row]] + rank[row]] = row;
}

// ---------------- Kernel 5: per-cluster accumulation (no atomics) ----------------
__global__ __launch_bounds__(512) void cluster_accum(
        const float* __restrict__ X, const float* __restrict__ W,
        const int* __restrict__ sorted, const int* __restrict__ offset,
        const int* __restrict__ count, float* __restrict__ out) {
    int k = blockIdx.x;
    int start = offset[k];
    int cnt = count[k];
    int lane = threadIdx.x & 63;
    int w = threadIdx.x >> 6;            // 8 waves
    float accx = 0.f, accw = 0.f;
    int i = w;
    int row_next = (i < cnt) ? sorted[start + i] : 0;
    for (; i < cnt; i += 8) {
        int row = row_next;
        row_next = (i + 8 < cnt) ? sorted[start + i + 8] : 0;  // prefetch next idx
        float xv = X[(size_t)row * D_DIM + lane];
        float wv = W[(size_t)row * D_DIM + lane];
        accx = fmaf(xv, wv, accx);
        accw += wv;
    }
    __shared__ float sx[8][D_DIM];
    __shared__ float sw[8][D_DIM];
    sx[w][lane] = accx;
    sw[w][lane] = accw;
    __syncthreads();
    if (w == 0) {
        float ax = 0.f, aw = 0.f;
#pragma unroll
        for (int j = 0; j < 8; ++j) { ax += sx[j][lane]; aw += sw[j][lane]; }
        out[(size_t)k * D_DIM + lane] = ax;
        out[(size_t)(K_CLUS + k) * D_DIM + lane] = aw;
    }
}

// ---------------- Kernel 6: broadcast inertia to row 2K ----------------
__global__ void finalize_kernel(const float* __restrict__ inertia_ws, float* __restrict__ out) {
    out[(size_t)(2 * K_CLUS) * D_DIM + threadIdx.x] = *inertia_ws;
}

// ---------------- Fallback (old atomic path) if ws too small ----------------
__global__ __launch_bounds__(256) void accum_atomic_kernel(
        const float* __restrict__ X, const float* __restrict__ W,
        const int* __restrict__ y, float* __restrict__ out, int n) {
    int row = blockIdx.x * blockDim.x + threadIdx.x;
    if (row >= n) return;
    int k = y[row];
    const float4* xp = (const float4*)(X + (size_t)row * D_DIM);
    const float4* wp = (const float4*)(W + (size_t)row * D_DIM);
    float* xw = out + (size_t)k * D_DIM;
    float* wsv = out + (size_t)(K_CLUS + k) * D_DIM;
#pragma unroll
    for (int i = 0; i < 16; ++i) {
        float4 x = xp[i];
        float4 wq = wp[i];
        atomicAdd(xw + 4 * i + 0, x.x * wq.x);
        atomicAdd(xw + 4 * i + 1, x.y * wq.y);
        atomicAdd(xw + 4 * i + 2, x.z * wq.z);
        atomicAdd(xw + 4 * i + 3, x.w * wq.w);
        atomicAdd(wsv + 4 * i + 0, wq.x);
        atomicAdd(wsv + 4 * i + 1, wq.y);
        atomicAdd(wsv + 4 * i + 2, wq.z);
        atomicAdd(wsv + 4 * i + 3, wq.w);
    }
}

extern "C" void kernel_launch(void* const* d_in, const int* in_sizes, int n_in,
                              void* d_out, int out_size, void* d_ws, size_t ws_size,
                              hipStream_t stream) {
    const float* X = (const float*)d_in[0];
    const float* C = (const float*)d_in[1];
    const float* W = (const float*)d_in[2];
    float* out = (float*)d_out;
    int n = in_sizes[0] / D_DIM;        // 500000
    int k_total = in_sizes[1] / D_DIM;  // 512

    // ws layout
    char* ws = (char*)d_ws;
    int*   count   = (int*)ws;                  // 512 ints
    float* inertia = (float*)(ws + 2048);       // 1 float
    float* cc      = (float*)(ws + 2560);       // 512 floats  (within first 8KB? no: 2560+2048=4608 <= 8192)
    int*   offset  = (int*)(ws + 8192);         // 512 ints
    int*   yv      = (int*)(ws + 16384);        // n ints
    int*   rank    = (int*)(ws + 16384 + (size_t)n * 4);
    int*   sorted  = (int*)(ws + 16384 + (size_t)n * 8);
    size_t needed  = 16384 + (size_t)n * 12;

    int nblk = (n + 255) / 256;

    if (ws_size >= needed) {
        // zero count + inertia each call (graph-replay safe)
        hipMemsetAsync(ws, 0, 4096, stream);
        cc_kernel<<<(k_total + 255) / 256, 256, 0, stream>>>(C, cc, k_total);
        assign_kernel<<<nblk, 256, 0, stream>>>(X, C, cc, yv, rank, count, inertia, n);
        prefix_kernel<<<1, K_CLUS, 0, stream>>>(count, offset);
        scatter_kernel<<<nblk, 256, 0, stream>>>(yv, rank, offset, sorted, n);
        cluster_accum<<<K_CLUS, 512, 0, stream>>>(X, W, sorted, offset, count, out);
        finalize_kernel<<<1, D_DIM, 0, stream>>>(inertia, out);
    } else {
        // fallback: old atomic path (ws needs 16KB + 4n)
        hipMemsetAsync(ws, 0, 4096, stream);
        hipMemsetAsync(d_out, 0, (size_t)out_size * sizeof(float), stream);
        cc_kernel<<<(k_total + 255) / 256, 256, 0, stream>>>(C, cc, k_total);
        assign_kernel<<<nblk, 256, 0, stream>>>(X, C, cc, yv, yv /*rank unused->y*/, count, inertia, n);
        accum_atomic_kernel<<<nblk, 256, 0, stream>>>(X, W, yv, out, n);
        finalize_kernel<<<1, D_DIM, 0, stream>>>(inertia, out);
    }
}

// Round 3
// 1572.171 us; speedup vs baseline: 8.0856x; 1.5624x over previous
//
#include <hip/hip_runtime.h>
#include <hip/hip_bf16.h>

// N=500000, D=64, K=512 (fp32).
// out rows: [0,K)=xw_sum, [K,2K)=w_sum, row 2K = inertia broadcast to 64 cols.

#define D_DIM 64
#define K_CLUS 512
#define SEG 8          // segments per cluster in accumulation
#define SEG_SHIFT 3

// ---------------- Kernel 1: half centroid squared norms ----------------
__global__ void cc_kernel(const float* __restrict__ C, float* __restrict__ CChalf, int k_total) {
    int k = blockIdx.x * blockDim.x + threadIdx.x;
    if (k >= k_total) return;
    const float4* cp = (const float4*)(C + (size_t)k * D_DIM);
    float s = 0.f;
#pragma unroll
    for (int i = 0; i < 16; ++i) {
        float4 c = cp[i];
        s += c.x * c.x + c.y * c.y + c.z * c.z + c.w * c.w;
    }
    CChalf[k] = 0.5f * s;
}

// ---------------- Kernel 2: assignment + histogram + inertia ----------------
// argmin_k ||x-c_k||^2  ==  argmax_k (x.c_k - 0.5*||c_k||^2)
__global__ __launch_bounds__(256) void assign_kernel(
        const float* __restrict__ X, const float* __restrict__ C,
        const float* __restrict__ CChalf, int* __restrict__ y,
        int* __restrict__ rank, int* __restrict__ count,
        float* __restrict__ inertia_ws, int n) {
    int row = blockIdx.x * blockDim.x + threadIdx.x;
    float mind = 0.f;
    if (row < n) {
        float4 x[16];
        const float4* xp = (const float4*)(X + (size_t)row * D_DIM);
#pragma unroll
        for (int i = 0; i < 16; ++i) x[i] = xp[i];
        float xx = 0.f;
#pragma unroll
        for (int i = 0; i < 16; ++i)
            xx += x[i].x * x[i].x + x[i].y * x[i].y + x[i].z * x[i].z + x[i].w * x[i].w;

        float best = -3.4e38f;
        int bestk = 0;
#pragma unroll 2
        for (int k = 0; k < K_CLUS; ++k) {
            const float4* cp = (const float4*)(C + (size_t)k * D_DIM);
            // 4 independent FMA chains (16 deep) to hide VALU latency
            float s0 = 0.f, s1 = 0.f, s2 = 0.f, s3 = 0.f;
#pragma unroll
            for (int i = 0; i < 16; i += 4) {
                float4 c0 = cp[i + 0], c1 = cp[i + 1], c2 = cp[i + 2], c3 = cp[i + 3];
                s0 += x[i + 0].x * c0.x + x[i + 0].y * c0.y + x[i + 0].z * c0.z + x[i + 0].w * c0.w;
                s1 += x[i + 1].x * c1.x + x[i + 1].y * c1.y + x[i + 1].z * c1.z + x[i + 1].w * c1.w;
                s2 += x[i + 2].x * c2.x + x[i + 2].y * c2.y + x[i + 2].z * c2.z + x[i + 2].w * c2.w;
                s3 += x[i + 3].x * c3.x + x[i + 3].y * c3.y + x[i + 3].z * c3.z + x[i + 3].w * c3.w;
            }
            float sc = (s0 + s1) + (s2 + s3) - CChalf[k];
            if (sc > best) { best = sc; bestk = k; }   // first-max == first-min dist
        }
        y[row] = bestk;
        rank[row] = atomicAdd(&count[bestk], 1);
        mind = sqrtf(fmaxf(xx - 2.f * best, 0.f) * (1.0f / (float)D_DIM));
    }
    // wave butterfly, block reduce, one atomic per block
    float s = mind;
#pragma unroll
    for (int off = 32; off > 0; off >>= 1) s += __shfl_xor(s, off);
    __shared__ float wsum[4];
    int w = threadIdx.x >> 6;
    if ((threadIdx.x & 63) == 0) wsum[w] = s;
    __syncthreads();
    if (threadIdx.x == 0)
        atomicAdd(inertia_ws, wsum[0] + wsum[1] + wsum[2] + wsum[3]);
}

// ---------------- Kernel 3: exclusive prefix sum over 512 counts ----------------
__global__ __launch_bounds__(K_CLUS) void prefix_kernel(
        const int* __restrict__ count, int* __restrict__ offset) {
    __shared__ int tmp[K_CLUS];
    int t = threadIdx.x;
    tmp[t] = count[t];
    __syncthreads();
    for (int s = 1; s < K_CLUS; s <<= 1) {
        int v = (t >= s) ? tmp[t - s] : 0;
        __syncthreads();
        tmp[t] += v;
        __syncthreads();
    }
    offset[t] = tmp[t] - count[t];   // exclusive
}

// ---------------- Kernel 4: scatter rows into cluster-sorted order ----------------
__global__ __launch_bounds__(256) void scatter_kernel(
        const int* __restrict__ y, const int* __restrict__ rank,
        const int* __restrict__ offset, int* __restrict__ sorted, int n) {
    int row = blockIdx.x * blockDim.x + threadIdx.x;
    if (row >= n) return;
    sorted[offset[y[row]] + rank[row]] = row;
}

// ---------------- Kernel 5: segmented per-cluster accumulation ----------------
// grid = K*SEG blocks x 256 threads (4 waves). Each block: one segment of one
// cluster. Partial sums -> LDS reduce -> 2 atomicAdds per lane (8-way
// contention per address, 512K atomics total).
__global__ __launch_bounds__(256) void cluster_accum_seg(
        const float* __restrict__ X, const float* __restrict__ W,
        const int* __restrict__ sorted, const int* __restrict__ offset,
        const int* __restrict__ count, float* __restrict__ out) {
    int bid = blockIdx.x;
    int k = bid >> SEG_SHIFT;
    int seg = bid & (SEG - 1);
    int cnt = count[k];
    int chunk = (cnt + SEG - 1) >> SEG_SHIFT;
    int lo = seg * chunk;
    int hi = min(cnt, lo + chunk);
    int start = offset[k];
    int lane = threadIdx.x & 63;
    int w = threadIdx.x >> 6;            // 4 waves

    float ax = 0.f, aw = 0.f;
    int i = lo + w;
    int next = (i < hi) ? sorted[start + i] : 0;
    for (; i < hi; i += 4) {
        int row = next;
        int i2 = i + 4;
        next = (i2 < hi) ? sorted[start + i2] : 0;   // prefetch next index
        float xv = X[(size_t)row * D_DIM + lane];
        float wv = W[(size_t)row * D_DIM + lane];
        ax = fmaf(xv, wv, ax);
        aw += wv;
    }
    __shared__ float sx[4][D_DIM];
    __shared__ float sw[4][D_DIM];
    sx[w][lane] = ax;
    sw[w][lane] = aw;
    __syncthreads();
    if (w == 0) {
        float tx = sx[0][lane] + sx[1][lane] + sx[2][lane] + sx[3][lane];
        float tw = sw[0][lane] + sw[1][lane] + sw[2][lane] + sw[3][lane];
        if (tx != 0.f || tw != 0.f || lo < hi) {
            atomicAdd(out + (size_t)k * D_DIM + lane, tx);
            atomicAdd(out + (size_t)(K_CLUS + k) * D_DIM + lane, tw);
        }
    }
}

// ---------------- Kernel 6: broadcast inertia to row 2K ----------------
__global__ void finalize_kernel(const float* __restrict__ inertia_ws, float* __restrict__ out) {
    out[(size_t)(2 * K_CLUS) * D_DIM + threadIdx.x] = *inertia_ws;
}

// ---------------- Fallback (atomic path) if ws too small ----------------
__global__ __launch_bounds__(256) void accum_atomic_kernel(
        const float* __restrict__ X, const float* __restrict__ W,
        const int* __restrict__ y, float* __restrict__ out, int n) {
    int row = blockIdx.x * blockDim.x + threadIdx.x;
    if (row >= n) return;
    int k = y[row];
    const float4* xp = (const float4*)(X + (size_t)row * D_DIM);
    const float4* wp = (const float4*)(W + (size_t)row * D_DIM);
    float* xw = out + (size_t)k * D_DIM;
    float* wsv = out + (size_t)(K_CLUS + k) * D_DIM;
#pragma unroll
    for (int i = 0; i < 16; ++i) {
        float4 x = xp[i];
        float4 wq = wp[i];
        atomicAdd(xw + 4 * i + 0, x.x * wq.x);
        atomicAdd(xw + 4 * i + 1, x.y * wq.y);
        atomicAdd(xw + 4 * i + 2, x.z * wq.z);
        atomicAdd(xw + 4 * i + 3, x.w * wq.w);
        atomicAdd(wsv + 4 * i + 0, wq.x);
        atomicAdd(wsv + 4 * i + 1, wq.y);
        atomicAdd(wsv + 4 * i + 2, wq.z);
        atomicAdd(wsv + 4 * i + 3, wq.w);
    }
}

extern "C" void kernel_launch(void* const* d_in, const int* in_sizes, int n_in,
                              void* d_out, int out_size, void* d_ws, size_t ws_size,
                              hipStream_t stream) {
    const float* X = (const float*)d_in[0];
    const float* C = (const float*)d_in[1];
    const float* W = (const float*)d_in[2];
    float* out = (float*)d_out;
    int n = in_sizes[0] / D_DIM;        // 500000
    int k_total = in_sizes[1] / D_DIM;  // 512

    char* ws = (char*)d_ws;
    int*   count   = (int*)ws;                  // 512 ints
    float* inertia = (float*)(ws + 2048);       // 1 float
    float* cc      = (float*)(ws + 2560);       // 512 floats
    int*   offset  = (int*)(ws + 8192);         // 512 ints
    int*   yv      = (int*)(ws + 16384);        // n ints
    int*   rank    = (int*)(ws + 16384 + (size_t)n * 4);
    int*   sorted  = (int*)(ws + 16384 + (size_t)n * 8);
    size_t needed  = 16384 + (size_t)n * 12;

    int nblk = (n + 255) / 256;

    // atomically-accumulated outputs -> zero every call (graph-replay safe)
    hipMemsetAsync(ws, 0, 4096, stream);
    hipMemsetAsync(d_out, 0, (size_t)out_size * sizeof(float), stream);
    cc_kernel<<<(k_total + 255) / 256, 256, 0, stream>>>(C, cc, k_total);

    if (ws_size >= needed) {
        assign_kernel<<<nblk, 256, 0, stream>>>(X, C, cc, yv, rank, count, inertia, n);
        prefix_kernel<<<1, K_CLUS, 0, stream>>>(count, offset);
        scatter_kernel<<<nblk, 256, 0, stream>>>(yv, rank, offset, sorted, n);
        cluster_accum_seg<<<k_total * SEG, 256, 0, stream>>>(X, W, sorted, offset, count, out);
        finalize_kernel<<<1, D_DIM, 0, stream>>>(inertia, out);
    } else {
        assign_kernel<<<nblk, 256, 0, stream>>>(X, C, cc, yv, yv, count, inertia, n);
        accum_atomic_kernel<<<nblk, 256, 0, stream>>>(X, W, yv, out, n);
        finalize_kernel<<<1, D_DIM, 0, stream>>>(inertia, out);
    }
}

// Round 4
// 581.493 us; speedup vs baseline: 21.8610x; 2.7037x over previous
//
#include <hip/hip_runtime.h>

// N=500000, D=64, K=512 (fp32 in/out).
// out rows: [0,K)=xw_sum, [K,2K)=w_sum, row 2K = inertia broadcast to 64 cols.

#define D_DIM 64
#define K_CLUS 512
#define SEG 16
#define SEG_SHIFT 4

typedef __attribute__((ext_vector_type(8))) short short8;
typedef __attribute__((ext_vector_type(4))) float f32x4;

__device__ inline float dot4sq(float4 a) {
    return a.x * a.x + a.y * a.y + a.z * a.z + a.w * a.w;
}
__device__ inline unsigned short bfb(float f) {   // fp32 -> bf16 bits, RNE
    unsigned int u = __float_as_uint(f);
    return (unsigned short)((u + 0x7FFFu + ((u >> 16) & 1u)) >> 16);
}
__device__ inline short8 pack8(float4 a, float4 b) {
    short8 r;
    r[0] = (short)bfb(a.x); r[1] = (short)bfb(a.y);
    r[2] = (short)bfb(a.z); r[3] = (short)bfb(a.w);
    r[4] = (short)bfb(b.x); r[5] = (short)bfb(b.y);
    r[6] = (short)bfb(b.z); r[7] = (short)bfb(b.w);
    return r;
}
__device__ inline float4 shfl_xor4(float4 v, int m) {
    float4 r;
    r.x = __shfl_xor(v.x, m); r.y = __shfl_xor(v.y, m);
    r.z = __shfl_xor(v.z, m); r.w = __shfl_xor(v.w, m);
    return r;
}

// ---------------- Kernel 1: half-norms + bf16 pack of centroids ----------------
__global__ void cc_kernel(const float* __restrict__ C, float* __restrict__ CChalf,
                          unsigned short* __restrict__ Cb, int k_total) {
    int k = blockIdx.x * blockDim.x + threadIdx.x;
    if (k >= k_total) return;
    const float4* cp = (const float4*)(C + (size_t)k * D_DIM);
    unsigned short* ob = Cb + (size_t)k * D_DIM;
    float s = 0.f;
#pragma unroll
    for (int i = 0; i < 16; ++i) {
        float4 c = cp[i];
        s += dot4sq(c);
        ob[4 * i + 0] = bfb(c.x); ob[4 * i + 1] = bfb(c.y);
        ob[4 * i + 2] = bfb(c.z); ob[4 * i + 3] = bfb(c.w);
    }
    CChalf[k] = 0.5f * s;
}

// ---------------- Kernel 2: MFMA assignment + histogram + inertia ----------------
// argmin_k ||x-c_k||^2 == argmax_k (x.c_k - 0.5||c_k||^2).
// Block: 512 thr / 8 waves; wave owns 16 rows x all 512 clusters.
// C (bf16) staged in LDS, XOR-swizzled vs the 128B row stride.
__global__ __launch_bounds__(512) void assign_mfma(
        const float* __restrict__ X, const unsigned short* __restrict__ Cb,
        const float* __restrict__ CChalf, int* __restrict__ y,
        int* __restrict__ rank, int* __restrict__ count,
        float* __restrict__ inertia_ws, int n) {
    __shared__ __align__(16) char c_lds[K_CLUS * D_DIM * 2];   // 64 KB
    __shared__ float cchalf_lds[K_CLUS];
    __shared__ float wsum8[8];
    int tid = threadIdx.x;

    // stage C_bf16 -> LDS with swizzle phys(row,b) = row*128 + (b ^ ((row&7)<<4))
    const uint4* Cb4 = (const uint4*)Cb;
#pragma unroll
    for (int it = 0; it < 8; ++it) {
        int c = tid + it * 512;               // 16B chunk id, 8 chunks per row
        uint4 v = Cb4[c];
        int row = c >> 3;
        int b = (c & 7) << 4;
        *(uint4*)(c_lds + (row << 7) + (b ^ ((row & 7) << 4))) = v;
    }
    cchalf_lds[tid] = CChalf[tid];            // 512 threads == K_CLUS

    int lane = tid & 63, wid = tid >> 6;
    int c15 = lane & 15, g = lane >> 4;       // A row = c15, k-group = g
    int rowbase = blockIdx.x * 128;
    int myrow = rowbase + wid * 16 + c15;
    int lrow = min(myrow, n - 1);

    const float4* X4 = (const float4*)X;
    size_t xb = (size_t)lrow * 16;
    float4 f0 = X4[xb + g * 2], f1 = X4[xb + g * 2 + 1];        // k = 8g..8g+7
    float4 f2 = X4[xb + 8 + g * 2], f3 = X4[xb + 9 + g * 2];    // k = 32+8g..
    float xs = dot4sq(f0) + dot4sq(f1) + dot4sq(f2) + dot4sq(f3);
    xs += __shfl_xor(xs, 16);
    xs += __shfl_xor(xs, 32);                 // xs = ||x_row(c15)||^2 (fp32)
    short8 a0 = pack8(f0, f1), a1 = pack8(f2, f3);
    __syncthreads();

    float best0 = -3.4e38f, best1 = -3.4e38f, best2 = -3.4e38f, best3 = -3.4e38f;
    int bk0 = 0, bk1 = 0, bk2 = 0, bk3 = 0;
    int g16 = g << 4;
    for (int tile = 0; tile < K_CLUS / 16; ++tile) {
        int col = (tile << 4) + c15;          // B col = cluster index
        float cch = cchalf_lds[col];
        f32x4 acc = {-cch, -cch, -cch, -cch}; // fold -0.5||c||^2 into acc init
        const char* bp = c_lds + (col << 7);
        int swz = (col & 7) << 4;
        short8 b0 = *(const short8*)(bp + (g16 ^ swz));
        short8 b1 = *(const short8*)(bp + ((g16 + 64) ^ swz));
        acc = __builtin_amdgcn_mfma_f32_16x16x32_bf16(a0, b0, acc, 0, 0, 0);
        acc = __builtin_amdgcn_mfma_f32_16x16x32_bf16(a1, b1, acc, 0, 0, 0);
        // D layout: col=lane&15, row=(lane>>4)*4+reg (m89-verified)
        if (acc[0] > best0) { best0 = acc[0]; bk0 = col; }
        if (acc[1] > best1) { best1 = acc[1]; bk1 = col; }
        if (acc[2] > best2) { best2 = acc[2]; bk2 = col; }
        if (acc[3] > best3) { best3 = acc[3]; bk3 = col; }
    }
    // argmax across the 16 lanes of each row-group (prefer lower k on ties)
    float best[4] = {best0, best1, best2, best3};
    int bestk[4] = {bk0, bk1, bk2, bk3};
#pragma unroll
    for (int off = 1; off < 16; off <<= 1) {
#pragma unroll
        for (int r2 = 0; r2 < 4; ++r2) {
            float so = __shfl_xor(best[r2], off);
            int ko = __shfl_xor(bestk[r2], off);
            if (so > best[r2] || (so == best[r2] && ko < bestk[r2])) {
                best[r2] = so; bestk[r2] = ko;
            }
        }
    }
    float mind = 0.f;
#pragma unroll
    for (int r2 = 0; r2 < 4; ++r2) {
        int r = (g << 2) + r2;                 // row index within wave
        float xxr = __shfl(xs, r);             // all lanes participate
        if (c15 == r2) {
            int grow = rowbase + (wid << 4) + r;
            if (grow < n) {
                y[grow] = bestk[r2];
                rank[grow] = atomicAdd(count + bestk[r2], 1);
                mind += sqrtf(fmaxf(xxr - 2.f * best[r2], 0.f) * (1.0f / 64.0f));
            }
        }
    }
#pragma unroll
    for (int off = 1; off < 64; off <<= 1) mind += __shfl_xor(mind, off);
    if (lane == 0) wsum8[wid] = mind;
    __syncthreads();
    if (tid == 0) {
        float s = 0.f;
#pragma unroll
        for (int j = 0; j < 8; ++j) s += wsum8[j];
        atomicAdd(inertia_ws, s);
    }
}

// ---------------- Kernel 3: exclusive prefix sum over 512 counts ----------------
__global__ __launch_bounds__(K_CLUS) void prefix_kernel(
        const int* __restrict__ count, int* __restrict__ offset) {
    __shared__ int tmp[K_CLUS];
    int t = threadIdx.x;
    tmp[t] = count[t];
    __syncthreads();
    for (int s = 1; s < K_CLUS; s <<= 1) {
        int v = (t >= s) ? tmp[t - s] : 0;
        __syncthreads();
        tmp[t] += v;
        __syncthreads();
    }
    offset[t] = tmp[t] - count[t];
}

// ---------------- Kernel 4: scatter rows into cluster-sorted order ----------------
__global__ __launch_bounds__(256) void scatter_kernel(
        const int* __restrict__ y, const int* __restrict__ rank,
        const int* __restrict__ offset, int* __restrict__ sorted, int n) {
    int row = blockIdx.x * blockDim.x + threadIdx.x;
    if (row >= n) return;
    sorted[offset[y[row]] + rank[row]] = row;
}

// ---------------- Kernel 5: segmented per-cluster accumulation ----------------
// grid = K*SEG x 256 thr. Wave: 4 rows/iter, 16 lanes x float4 per row.
__global__ __launch_bounds__(256) void cluster_accum_seg(
        const float* __restrict__ X, const float* __restrict__ W,
        const int* __restrict__ sorted, const int* __restrict__ offset,
        const int* __restrict__ count, float* __restrict__ out) {
    int bid = blockIdx.x;
    int k = bid >> SEG_SHIFT;
    int seg = bid & (SEG - 1);
    int cnt = count[k];
    int chunk = (cnt + SEG - 1) >> SEG_SHIFT;
    int lo = seg * chunk;
    int hi = min(cnt, lo + chunk);
    int start = offset[k];
    int lane = threadIdx.x & 63, w = threadIdx.x >> 6;
    int rsub = lane >> 4, col4 = lane & 15;
    const float4* X4 = (const float4*)X;
    const float4* W4 = (const float4*)W;

    float4 ax = {0.f, 0.f, 0.f, 0.f}, aw = {0.f, 0.f, 0.f, 0.f};
    for (int base = lo + w * 4; base < hi; base += 16) {
        int ii = base + rsub;
        if (ii < hi) {
            int row = sorted[start + ii];
            float4 xv = X4[(size_t)row * 16 + col4];
            float4 wv = W4[(size_t)row * 16 + col4];
            ax.x = fmaf(xv.x, wv.x, ax.x); ax.y = fmaf(xv.y, wv.y, ax.y);
            ax.z = fmaf(xv.z, wv.z, ax.z); ax.w = fmaf(xv.w, wv.w, ax.w);
            aw.x += wv.x; aw.y += wv.y; aw.z += wv.z; aw.w += wv.w;
        }
    }
    float4 t;
    t = shfl_xor4(ax, 16); ax.x += t.x; ax.y += t.y; ax.z += t.z; ax.w += t.w;
    t = shfl_xor4(ax, 32); ax.x += t.x; ax.y += t.y; ax.z += t.z; ax.w += t.w;
    t = shfl_xor4(aw, 16); aw.x += t.x; aw.y += t.y; aw.z += t.z; aw.w += t.w;
    t = shfl_xor4(aw, 32); aw.x += t.x; aw.y += t.y; aw.z += t.z; aw.w += t.w;

    __shared__ float4 sx4[4][16];
    __shared__ float4 sw4[4][16];
    if (lane < 16) { sx4[w][lane] = ax; sw4[w][lane] = aw; }
    __syncthreads();
    if (threadIdx.x < 16) {
        int c = threadIdx.x;
        float4 tx = {0.f, 0.f, 0.f, 0.f}, tw = {0.f, 0.f, 0.f, 0.f};
#pragma unroll
        for (int j = 0; j < 4; ++j) {
            float4 a = sx4[j][c], b = sw4[j][c];
            tx.x += a.x; tx.y += a.y; tx.z += a.z; tx.w += a.w;
            tw.x += b.x; tw.y += b.y; tw.z += b.z; tw.w += b.w;
        }
        float* xw = out + (size_t)k * D_DIM + c * 4;
        float* wp = out + (size_t)(K_CLUS + k) * D_DIM + c * 4;
        atomicAdd(xw + 0, tx.x); atomicAdd(xw + 1, tx.y);
        atomicAdd(xw + 2, tx.z); atomicAdd(xw + 3, tx.w);
        atomicAdd(wp + 0, tw.x); atomicAdd(wp + 1, tw.y);
        atomicAdd(wp + 2, tw.z); atomicAdd(wp + 3, tw.w);
    }
}

// ---------------- Kernel 6: broadcast inertia ----------------
__global__ void finalize_kernel(const float* __restrict__ inertia_ws, float* __restrict__ out) {
    out[(size_t)(2 * K_CLUS) * D_DIM + threadIdx.x] = *inertia_ws;
}

// ---------------- Fallback path (ws too small): scalar assign + atomic accum ----
__global__ __launch_bounds__(256) void assign_scalar(
        const float* __restrict__ X, const float* __restrict__ C,
        const float* __restrict__ CChalf, int* __restrict__ y,
        int* __restrict__ count, float* __restrict__ inertia_ws, int n) {
    int row = blockIdx.x * blockDim.x + threadIdx.x;
    float mind = 0.f;
    if (row < n) {
        float4 x[16];
        const float4* xp = (const float4*)(X + (size_t)row * D_DIM);
#pragma unroll
        for (int i = 0; i < 16; ++i) x[i] = xp[i];
        float xx = 0.f;
#pragma unroll
        for (int i = 0; i < 16; ++i) xx += dot4sq(x[i]);
        float best = -3.4e38f;
        int bestk = 0;
        for (int k = 0; k < K_CLUS; ++k) {
            const float4* cp = (const float4*)(C + (size_t)k * D_DIM);
            float s0 = 0.f;
#pragma unroll
            for (int i = 0; i < 16; ++i) {
                float4 c = cp[i];
                s0 += x[i].x * c.x + x[i].y * c.y + x[i].z * c.z + x[i].w * c.w;
            }
            float sc = s0 - CChalf[k];
            if (sc > best) { best = sc; bestk = k; }
        }
        y[row] = bestk;
        atomicAdd(&count[bestk], 1);
        mind = sqrtf(fmaxf(xx - 2.f * best, 0.f) * (1.0f / 64.0f));
    }
    float s = mind;
#pragma unroll
    for (int off = 32; off > 0; off >>= 1) s += __shfl_xor(s, off);
    __shared__ float wsum[4];
    int w = threadIdx.x >> 6;
    if ((threadIdx.x & 63) == 0) wsum[w] = s;
    __syncthreads();
    if (threadIdx.x == 0)
        atomicAdd(inertia_ws, wsum[0] + wsum[1] + wsum[2] + wsum[3]);
}

__global__ __launch_bounds__(256) void accum_atomic_kernel(
        const float* __restrict__ X, const float* __restrict__ W,
        const int* __restrict__ y, float* __restrict__ out, int n) {
    int row = blockIdx.x * blockDim.x + threadIdx.x;
    if (row >= n) return;
    int k = y[row];
    const float4* xp = (const float4*)(X + (size_t)row * D_DIM);
    const float4* wp = (const float4*)(W + (size_t)row * D_DIM);
    float* xw = out + (size_t)k * D_DIM;
    float* wsv = out + (size_t)(K_CLUS + k) * D_DIM;
#pragma unroll
    for (int i = 0; i < 16; ++i) {
        float4 x = xp[i];
        float4 wq = wp[i];
        atomicAdd(xw + 4 * i + 0, x.x * wq.x);
        atomicAdd(xw + 4 * i + 1, x.y * wq.y);
        atomicAdd(xw + 4 * i + 2, x.z * wq.z);
        atomicAdd(xw + 4 * i + 3, x.w * wq.w);
        atomicAdd(wsv + 4 * i + 0, wq.x);
        atomicAdd(wsv + 4 * i + 1, wq.y);
        atomicAdd(wsv + 4 * i + 2, wq.z);
        atomicAdd(wsv + 4 * i + 3, wq.w);
    }
}

extern "C" void kernel_launch(void* const* d_in, const int* in_sizes, int n_in,
                              void* d_out, int out_size, void* d_ws, size_t ws_size,
                              hipStream_t stream) {
    const float* X = (const float*)d_in[0];
    const float* C = (const float*)d_in[1];
    const float* W = (const float*)d_in[2];
    float* out = (float*)d_out;
    int n = in_sizes[0] / D_DIM;        // 500000
    int k_total = in_sizes[1] / D_DIM;  // 512

    char* ws = (char*)d_ws;
    int*            count   = (int*)ws;                    // 2 KB
    float*          inertia = (float*)(ws + 2048);
    float*          cchalf  = (float*)(ws + 2560);         // 2 KB
    int*            offset  = (int*)(ws + 8192);           // 2 KB
    unsigned short* Cb      = (unsigned short*)(ws + 12288); // 64 KB bf16 C
    int*            yv      = (int*)(ws + 81920);
    int*            rank    = (int*)(ws + 81920 + (size_t)n * 4);
    int*            sorted  = (int*)(ws + 81920 + (size_t)n * 8);
    size_t needed = 81920 + (size_t)n * 12;

    int nblk = (n + 255) / 256;

    hipMemsetAsync(ws, 0, 4096, stream);                       // count + inertia
    hipMemsetAsync(d_out, 0, (size_t)out_size * sizeof(float), stream);
    cc_kernel<<<(k_total + 255) / 256, 256, 0, stream>>>(C, cchalf, Cb, k_total);

    if (ws_size >= needed) {
        assign_mfma<<<(n + 127) / 128, 512, 0, stream>>>(X, Cb, cchalf, yv, rank, count, inertia, n);
        prefix_kernel<<<1, K_CLUS, 0, stream>>>(count, offset);
        scatter_kernel<<<nblk, 256, 0, stream>>>(yv, rank, offset, sorted, n);
        cluster_accum_seg<<<k_total * SEG, 256, 0, stream>>>(X, W, sorted, offset, count, out);
        finalize_kernel<<<1, D_DIM, 0, stream>>>(inertia, out);
    } else {
        assign_scalar<<<nblk, 256, 0, stream>>>(X, C, cchalf, yv, count, inertia, n);
        accum_atomic_kernel<<<nblk, 256, 0, stream>>>(X, W, yv, out, n);
        finalize_kernel<<<1, D_DIM, 0, stream>>>(inertia, out);
    }
}